// Round 3
// baseline (294.977 us; speedup 1.0000x reference)
//
#include <hip/hip_runtime.h>
#include <hip/hip_bf16.h>
#include <float.h>

using bf16 = __hip_bfloat16;
typedef __attribute__((ext_vector_type(8))) short bf16x8;
typedef __attribute__((ext_vector_type(4))) float f32x4;
typedef __attribute__((ext_vector_type(16))) float f32x16;

#define DIM   1024
#define NSEQ  4096
#define BATCH 2
#define NH    16
#define HD    64
#define NSEG  8
#define MSEG  512
#define ROWS  (BATCH*NSEQ)   // 8192
#define NC    (BATCH*NH)     // 32

__device__ __forceinline__ void gload16(const bf16* g, bf16* l) {
    __builtin_amdgcn_global_load_lds((const __attribute__((address_space(1))) unsigned int*)g,
                                     (__attribute__((address_space(3))) unsigned int*)l, 16, 0, 0);
}

// ---------------------------------------------------------------- rope table
__global__ void k_rope_tab(float* __restrict__ cosT, float* __restrict__ sinT) {
    int idx = blockIdx.x * 256 + threadIdx.x;     // 4096*32 = 131072
    int t = idx >> 5, i = idx & 31;
    float freq = 1.0f / powf(10000.0f, (float)(2 * i) * (1.0f / 64.0f));
    float a = (float)t * freq;
    cosT[idx] = cosf(a);
    sinT[idx] = sinf(a);
}

// ---------------------------------------------------------------- x -> bf16
__global__ void k_convert_x(const float* __restrict__ X, bf16* __restrict__ Xb) {
    int i = (blockIdx.x * 256 + threadIdx.x) * 4;
    float4 v = *(const float4*)&X[i];
    union { bf16 h[4]; uint2 u; } p;
    p.h[0] = __float2bfloat16(v.x);
    p.h[1] = __float2bfloat16(v.y);
    p.h[2] = __float2bfloat16(v.z);
    p.h[3] = __float2bfloat16(v.w);
    *(uint2*)&Xb[i] = p.u;
}

// ------------------------------------------- W[k][n] -> Wt[n][k] (bf16)
__global__ void k_transpose(const float* __restrict__ W, bf16* __restrict__ Wt) {
    __shared__ float tile[32][33];
    int bx = blockIdx.x * 32;   // n
    int by = blockIdx.y * 32;   // k
    int tx = threadIdx.x;
    for (int i = threadIdx.y; i < 32; i += 8)
        tile[i][tx] = W[(size_t)(by + i) * DIM + bx + tx];
    __syncthreads();
    for (int i = threadIdx.y; i < 32; i += 8)
        Wt[(size_t)(bx + i) * DIM + by + tx] = __float2bfloat16(tile[tx][i]);
}

// ---------------------------------------------------------------- GEMM core (m97 structure)
__launch_bounds__(256, 2)
__global__ void k_gemm_proj(const bf16* __restrict__ A, const bf16* __restrict__ Bt,
                            float* __restrict__ C) {
    __shared__ alignas(16) bf16 As[128 * 32];
    __shared__ alignas(16) bf16 Bs[128 * 32];
    const int K = DIM;
    int tid = threadIdx.x;
    int lane = tid & 63, wave = tid >> 6;
    int wr = (wave >> 1) * 64, wc = (wave & 1) * 64;
    int m0 = blockIdx.y * 128, n0 = blockIdx.x * 128;
    int row = lane & 15, kk = (lane >> 4) * 8;
    int ch0 = wave * 128 + lane;
    int ch1 = ch0 + 64;
    int r0 = ch0 >> 2, c0e = (ch0 & 3) * 8;
    int r1 = ch1 >> 2, c1e = (ch1 & 3) * 8;
    bf16* ldsA0 = &As[wave * 1024];
    bf16* ldsA1 = &As[wave * 1024 + 512];
    bf16* ldsB0 = &Bs[wave * 1024];
    bf16* ldsB1 = &Bs[wave * 1024 + 512];
    f32x4 acc[4][4] = {};
    for (int k0 = 0; k0 < K; k0 += 32) {
        __syncthreads();
        gload16(&A[(size_t)(m0 + r0) * K + k0 + c0e], ldsA0);
        gload16(&A[(size_t)(m0 + r1) * K + k0 + c1e], ldsA1);
        gload16(&Bt[(size_t)(n0 + r0) * K + k0 + c0e], ldsB0);
        gload16(&Bt[(size_t)(n0 + r1) * K + k0 + c1e], ldsB1);
        __syncthreads();
        bf16x8 af[4], bfr[4];
#pragma unroll
        for (int mt = 0; mt < 4; ++mt) af[mt] = *(const bf16x8*)&As[(wr + mt * 16 + row) * 32 + kk];
#pragma unroll
        for (int nt = 0; nt < 4; ++nt) bfr[nt] = *(const bf16x8*)&Bs[(wc + nt * 16 + row) * 32 + kk];
#pragma unroll
        for (int mt = 0; mt < 4; ++mt)
#pragma unroll
            for (int nt = 0; nt < 4; ++nt)
                acc[mt][nt] = __builtin_amdgcn_mfma_f32_16x16x32_bf16(af[mt], bfr[nt], acc[mt][nt], 0, 0, 0);
    }
    int orow = (lane >> 4) * 4, ocol = lane & 15;
#pragma unroll
    for (int mt = 0; mt < 4; ++mt)
#pragma unroll
        for (int nt = 0; nt < 4; ++nt)
#pragma unroll
            for (int i = 0; i < 4; ++i)
                C[(size_t)(m0 + wr + mt * 16 + orow + i) * DIM + n0 + wc + nt * 16 + ocol] = acc[mt][nt][i];
}

// final GEMM: per-row-tile weight/bias select, fp32 out
__launch_bounds__(256, 2)
__global__ void k_gemm_out(const bf16* __restrict__ A, const bf16* __restrict__ Bt0,
                           const bf16* __restrict__ Bt1, const float* __restrict__ bias0,
                           const float* __restrict__ bias1, float* __restrict__ C) {
    __shared__ alignas(16) bf16 As[128 * 32];
    __shared__ alignas(16) bf16 Bs[128 * 32];
    const int K = DIM;
    int tid = threadIdx.x;
    int lane = tid & 63, wave = tid >> 6;
    int wr = (wave >> 1) * 64, wc = (wave & 1) * 64;
    int m0 = blockIdx.y * 128, n0 = blockIdx.x * 128;
    bool first = (m0 & (NSEQ - 1)) < MSEG;
    const bf16* Bt = first ? Bt0 : Bt1;
    const float* bias = first ? bias0 : bias1;
    int row = lane & 15, kk = (lane >> 4) * 8;
    int ch0 = wave * 128 + lane;
    int ch1 = ch0 + 64;
    int r0 = ch0 >> 2, c0e = (ch0 & 3) * 8;
    int r1 = ch1 >> 2, c1e = (ch1 & 3) * 8;
    bf16* ldsA0 = &As[wave * 1024];
    bf16* ldsA1 = &As[wave * 1024 + 512];
    bf16* ldsB0 = &Bs[wave * 1024];
    bf16* ldsB1 = &Bs[wave * 1024 + 512];
    f32x4 acc[4][4] = {};
    for (int k0 = 0; k0 < K; k0 += 32) {
        __syncthreads();
        gload16(&A[(size_t)(m0 + r0) * K + k0 + c0e], ldsA0);
        gload16(&A[(size_t)(m0 + r1) * K + k0 + c1e], ldsA1);
        gload16(&Bt[(size_t)(n0 + r0) * K + k0 + c0e], ldsB0);
        gload16(&Bt[(size_t)(n0 + r1) * K + k0 + c1e], ldsB1);
        __syncthreads();
        bf16x8 af[4], bfr[4];
#pragma unroll
        for (int mt = 0; mt < 4; ++mt) af[mt] = *(const bf16x8*)&As[(wr + mt * 16 + row) * 32 + kk];
#pragma unroll
        for (int nt = 0; nt < 4; ++nt) bfr[nt] = *(const bf16x8*)&Bs[(wc + nt * 16 + row) * 32 + kk];
#pragma unroll
        for (int mt = 0; mt < 4; ++mt)
#pragma unroll
            for (int nt = 0; nt < 4; ++nt)
                acc[mt][nt] = __builtin_amdgcn_mfma_f32_16x16x32_bf16(af[mt], bfr[nt], acc[mt][nt], 0, 0, 0);
    }
    int orow = (lane >> 4) * 4, ocol = lane & 15;
#pragma unroll
    for (int mt = 0; mt < 4; ++mt)
#pragma unroll
        for (int nt = 0; nt < 4; ++nt) {
            float bv = bias[n0 + wc + nt * 16 + ocol];
#pragma unroll
            for (int i = 0; i < 4; ++i)
                C[(size_t)(m0 + wr + mt * 16 + orow + i) * DIM + n0 + wc + nt * 16 + ocol] = acc[mt][nt][i] + bv;
        }
}

// ---------------------------------------------------------------- RoPE (Q)
__global__ void k_rope_q(const float* __restrict__ Y, const float* __restrict__ cosT,
                         const float* __restrict__ sinT, bf16* __restrict__ Qb) {
    int idx = blockIdx.x * 256 + threadIdx.x;   // ROWS*DIM/2 threads
    int e = idx & 31;
    int head = (idx >> 5) & 15;
    int rowg = idx >> 9;                        // 0..8191
    int t = rowg & (NSEQ - 1), bidx = rowg >> 12;
    float x1 = Y[(size_t)rowg * DIM + head * HD + e];
    float x2 = Y[(size_t)rowg * DIM + head * HD + e + 32];
    float cv = cosT[t * 32 + e], sv = sinT[t * 32 + e];
    float o1 = (x1 * cv - x2 * sv) * 0.125f;    // * d^-0.5
    float o2 = (x2 * cv + x1 * sv) * 0.125f;
    int c = bidx * NH + head;
    size_t base = ((size_t)c * NSEQ + t) * HD;
    Qb[base + e]      = __float2bfloat16(o1);
    Qb[base + e + 32] = __float2bfloat16(o2);
}

// ---------------------------------------------------------------- RoPE (KV) + transpose
__global__ void k_rope_kv(const float* __restrict__ Y, const float* __restrict__ cosT,
                          const float* __restrict__ sinT, bf16* __restrict__ KVb,
                          bf16* __restrict__ KVt) {
    int idx = blockIdx.x * 256 + threadIdx.x;
    int e = idx & 31;
    int head = (idx >> 5) & 15;
    int rowg = idx >> 9;
    int t = rowg & (NSEQ - 1), bidx = rowg >> 12;
    float x1 = Y[(size_t)rowg * DIM + head * HD + e];
    float x2 = Y[(size_t)rowg * DIM + head * HD + e + 32];
    float cv = cosT[t * 32 + e], sv = sinT[t * 32 + e];
    float o1 = x1 * cv - x2 * sv;
    float o2 = x2 * cv + x1 * sv;
    int c = bidx * NH + head;
    size_t base = ((size_t)c * NSEQ + t) * HD;
    KVb[base + e]      = __float2bfloat16(o1);
    KVb[base + e + 32] = __float2bfloat16(o2);
    KVt[((size_t)c * HD + e) * NSEQ + t]      = __float2bfloat16(o1);
    KVt[((size_t)c * HD + e + 32) * NSEQ + t] = __float2bfloat16(o2);
}

// ---------------------------------------------------------------- attention (swapped-QK 32x32)
// grid: 1024 linear blocks, XCD-swizzled; block 256 = 4 waves; wave = 32 q-rows; no LDS
__launch_bounds__(256, 2)
__global__ void k_attn(const bf16* __restrict__ Qb, const bf16* __restrict__ KVb,
                       const bf16* __restrict__ KVt, bf16* __restrict__ Ob) {
    int lane = threadIdx.x & 63, wave = threadIdx.x >> 6;
    int hi = lane >> 5, lq = lane & 31;
    // XCD-aware bijective swizzle: each XCD gets a contiguous chunk of 128 logical blocks
    // logical flatten: swz = bx + 4*seg + 32*c  (bx = rowgroup 0..3)
    int id = blockIdx.x;
    int swz = (id & 7) * 128 + (id >> 3);
    int bx = swz & 3, seg = (swz >> 2) & 7, c = swz >> 5;
    int i0 = bx * 128 + wave * 32;              // q-row offset within segment
    int bidx = c >> 4, head = c & 15;
    int tq = seg * MSEG + i0 + lq;
    const bf16* qptr = &Qb[((size_t)c * NSEQ + tq) * HD + hi * 8];
    bf16x8 qf[4];
#pragma unroll
    for (int dc = 0; dc < 4; ++dc) qf[dc] = *(const bf16x8*)&qptr[dc * 16];
    f32x16 o0 = {}, o1 = {};
    float mrun = -FLT_MAX, lrun = 0.f;
    int kvbase = (seg == 0) ? 0 : (seg - 1) * MSEG;
    int cstart = (seg == 0) ? 0 : MSEG;         // cols >= cstart are causal vs local row
    int cend = cstart + i0 + 32;

    const bf16* kbase = &KVb[((size_t)c * NSEQ + kvbase + lq) * HD + hi * 8];
    const bf16* vbase = &KVt[((size_t)c * HD + lq) * NSEQ + kvbase + hi * 8];

    bf16x8 kf[4], vf[4];
#pragma unroll
    for (int r = 0; r < 4; ++r) kf[r] = *(const bf16x8*)&kbase[r * 16];
    vf[0] = *(const bf16x8*)&vbase[0];
    vf[1] = *(const bf16x8*)&vbase[16];
    vf[2] = *(const bf16x8*)&vbase[(size_t)32 * NSEQ];
    vf[3] = *(const bf16x8*)&vbase[(size_t)32 * NSEQ + 16];

    for (int c0 = 0; c0 < cend; c0 += 32) {
        // ---- prefetch next chunk's K/V fragments (in flight across this chunk's compute)
        bf16x8 nk[4], nv[4];
        bool more = (c0 + 32) < cend;
        if (more) {
            const bf16* kp = kbase + (size_t)(c0 + 32) * HD;
            const bf16* vp = vbase + (c0 + 32);
#pragma unroll
            for (int r = 0; r < 4; ++r) nk[r] = *(const bf16x8*)&kp[r * 16];
            nv[0] = *(const bf16x8*)&vp[0];
            nv[1] = *(const bf16x8*)&vp[16];
            nv[2] = *(const bf16x8*)&vp[(size_t)32 * NSEQ];
            nv[3] = *(const bf16x8*)&vp[(size_t)32 * NSEQ + 16];
        }
        // ---- S^T[kv][q] : lane holds q=lq, kv = (r&3)+8*(r>>2)+4*hi
        f32x16 s = {};
        __builtin_amdgcn_s_setprio(1);
        s = __builtin_amdgcn_mfma_f32_32x32x16_bf16(kf[0], qf[0], s, 0, 0, 0);
        s = __builtin_amdgcn_mfma_f32_32x32x16_bf16(kf[1], qf[1], s, 0, 0, 0);
        s = __builtin_amdgcn_mfma_f32_32x32x16_bf16(kf[2], qf[2], s, 0, 0, 0);
        s = __builtin_amdgcn_mfma_f32_32x32x16_bf16(kf[3], qf[3], s, 0, 0, 0);
        __builtin_amdgcn_s_setprio(0);
        if (c0 + 31 >= cstart && c0 + 31 - cstart > i0) {
#pragma unroll
            for (int r = 0; r < 16; ++r) {
                int kvg = c0 + ((r & 3) + 8 * (r >> 2) + 4 * hi);
                if (kvg >= cstart && kvg - cstart > i0 + lq) s[r] = -FLT_MAX;
            }
        }
        // ---- online softmax (tree reductions; half the kv row lives in lane^32)
        float t8[8], t4[4];
#pragma unroll
        for (int r = 0; r < 8; ++r) t8[r] = fmaxf(s[2 * r], s[2 * r + 1]);
#pragma unroll
        for (int r = 0; r < 4; ++r) t4[r] = fmaxf(t8[2 * r], t8[2 * r + 1]);
        float vmax = fmaxf(fmaxf(t4[0], t4[1]), fmaxf(t4[2], t4[3]));
        vmax = fmaxf(vmax, __shfl_xor(vmax, 32));
        float nm = fmaxf(mrun, vmax);
        float al = __expf(mrun - nm);
        float p[16];
#pragma unroll
        for (int r = 0; r < 16; ++r) p[r] = __expf(s[r] - nm);
        float a8[8], a4[4];
#pragma unroll
        for (int r = 0; r < 8; ++r) a8[r] = p[2 * r] + p[2 * r + 1];
#pragma unroll
        for (int r = 0; r < 4; ++r) a4[r] = a8[2 * r] + a8[2 * r + 1];
        float sum = (a4[0] + a4[1]) + (a4[2] + a4[3]);
        sum += __shfl_xor(sum, 32);
        lrun = lrun * al + sum;
        mrun = nm;
#pragma unroll
        for (int r = 0; r < 16; ++r) { o0[r] *= al; o1[r] *= al; }
        // ---- P^T -> B-fragment: pack pairs to bf16, exchange halves via shfl_xor(32)
        unsigned pk[8], sw[8];
#pragma unroll
        for (int k = 0; k < 8; ++k) {
            union { bf16 h[2]; unsigned u; } cv;
            cv.h[0] = __float2bfloat16(p[2 * k]);
            cv.h[1] = __float2bfloat16(p[2 * k + 1]);
            pk[k] = cv.u;
        }
#pragma unroll
        for (int k = 0; k < 8; ++k) sw[k] = (unsigned)__shfl_xor((int)pk[k], 32);
        union { unsigned u[4]; bf16x8 v; } b0, b1;
        if (hi == 0) {
            b0.u[0] = pk[0]; b0.u[1] = pk[1]; b0.u[2] = sw[0]; b0.u[3] = sw[1];
            b1.u[0] = pk[4]; b1.u[1] = pk[5]; b1.u[2] = sw[4]; b1.u[3] = sw[5];
        } else {
            b0.u[0] = sw[2]; b0.u[1] = sw[3]; b0.u[2] = pk[2]; b0.u[3] = pk[3];
            b1.u[0] = sw[6]; b1.u[1] = sw[7]; b1.u[2] = pk[6]; b1.u[3] = pk[7];
        }
        // ---- O^T[d][q] += V^T P^T
        __builtin_amdgcn_s_setprio(1);
        o0 = __builtin_amdgcn_mfma_f32_32x32x16_bf16(vf[0], b0.v, o0, 0, 0, 0);
        o0 = __builtin_amdgcn_mfma_f32_32x32x16_bf16(vf[1], b1.v, o0, 0, 0, 0);
        o1 = __builtin_amdgcn_mfma_f32_32x32x16_bf16(vf[2], b0.v, o1, 0, 0, 0);
        o1 = __builtin_amdgcn_mfma_f32_32x32x16_bf16(vf[3], b1.v, o1, 0, 0, 0);
        __builtin_amdgcn_s_setprio(0);
        if (more) {
#pragma unroll
            for (int r = 0; r < 4; ++r) { kf[r] = nk[r]; vf[r] = nv[r]; }
        }
    }
    float inv = 1.0f / lrun;
    size_t obase = ((size_t)bidx * NSEQ + tq) * DIM + head * HD;
#pragma unroll
    for (int dt = 0; dt < 2; ++dt)
#pragma unroll
        for (int a = 0; a < 4; ++a) {
            union { bf16 h[4]; uint2 u; } pkd;
            const f32x16& ov = dt ? o1 : o0;
#pragma unroll
            for (int i = 0; i < 4; ++i) pkd.h[i] = __float2bfloat16(ov[4 * a + i] * inv);
            *(uint2*)&Ob[obase + dt * 32 + 8 * a + 4 * hi] = pkd.u;
        }
}

// ---------------------------------------------------------------- launch
extern "C" void kernel_launch(void* const* d_in, const int* in_sizes, int n_in,
                              void* d_out, int out_size, void* d_ws, size_t ws_size,
                              hipStream_t stream) {
    const float* x   = (const float*)d_in[0];
    const float* Wq  = (const float*)d_in[1];
    const float* Wkv = (const float*)d_in[2];
    const float* Wo  = (const float*)d_in[3];
    const float* bo  = (const float*)d_in[4];
    const float* Wo0 = (const float*)d_in[5];
    const float* bo0 = (const float*)d_in[6];
    float* out = (float*)d_out;

    char* ws = (char*)d_ws;
    size_t off = 0;
    auto alloc = [&](size_t bytes) { void* p = ws + off; off += (bytes + 255) & ~(size_t)255; return p; };
    float* cosT = (float*)alloc((size_t)NSEQ * 32 * 4);
    float* sinT = (float*)alloc((size_t)NSEQ * 32 * 4);
    bf16* Xb    = (bf16*)alloc((size_t)ROWS * DIM * 2);
    bf16* WqT   = (bf16*)alloc((size_t)DIM * DIM * 2);
    bf16* WkvT  = (bf16*)alloc((size_t)DIM * DIM * 2);
    bf16* WoT   = (bf16*)alloc((size_t)DIM * DIM * 2);
    bf16* Wo0T  = (bf16*)alloc((size_t)DIM * DIM * 2);
    float* Y    = (float*)alloc((size_t)ROWS * DIM * 4);
    bf16* Qb    = (bf16*)alloc((size_t)NC * NSEQ * HD * 2);
    bf16* KVb   = (bf16*)alloc((size_t)NC * NSEQ * HD * 2);
    bf16* KVt   = (bf16*)alloc((size_t)NC * HD * NSEQ * 2);
    bf16* Ob    = (bf16*)alloc((size_t)ROWS * DIM * 2);

    hipLaunchKernelGGL(k_rope_tab, dim3(NSEQ * 32 / 256), dim3(256), 0, stream, cosT, sinT);
    hipLaunchKernelGGL(k_convert_x, dim3(ROWS * DIM / 4 / 256), dim3(256), 0, stream, x, Xb);
    hipLaunchKernelGGL(k_transpose, dim3(32, 32), dim3(32, 8), 0, stream, Wq, WqT);
    hipLaunchKernelGGL(k_transpose, dim3(32, 32), dim3(32, 8), 0, stream, Wkv, WkvT);
    hipLaunchKernelGGL(k_transpose, dim3(32, 32), dim3(32, 8), 0, stream, Wo, WoT);
    hipLaunchKernelGGL(k_transpose, dim3(32, 32), dim3(32, 8), 0, stream, Wo0, Wo0T);

    hipLaunchKernelGGL(k_gemm_proj, dim3(8, 64), dim3(256), 0, stream, Xb, WqT, Y);
    hipLaunchKernelGGL(k_rope_q, dim3(ROWS * DIM / 2 / 256), dim3(256), 0, stream, Y, cosT, sinT, Qb);
    hipLaunchKernelGGL(k_gemm_proj, dim3(8, 64), dim3(256), 0, stream, Xb, WkvT, Y);
    hipLaunchKernelGGL(k_rope_kv, dim3(ROWS * DIM / 2 / 256), dim3(256), 0, stream, Y, cosT, sinT, KVb, KVt);

    hipLaunchKernelGGL(k_attn, dim3(1024), dim3(256), 0, stream, Qb, KVb, KVt, Ob);

    hipLaunchKernelGGL(k_gemm_out, dim3(8, 64), dim3(256), 0, stream, Ob, Wo0T, WoT, bo0, bo, out);
}

// Round 4
// 263.486 us; speedup vs baseline: 1.1195x; 1.1195x over previous
//
#include <hip/hip_runtime.h>
#include <hip/hip_bf16.h>
#include <float.h>

using bf16 = __hip_bfloat16;
typedef __attribute__((ext_vector_type(8))) short bf16x8;
typedef __attribute__((ext_vector_type(4))) float f32x4;
typedef __attribute__((ext_vector_type(16))) float f32x16;

#define DIM   1024
#define NSEQ  4096
#define BATCH 2
#define NH    16
#define HD    64
#define NSEG  8
#define MSEG  512
#define ROWS  (BATCH*NSEQ)   // 8192
#define NC    (BATCH*NH)     // 32

__device__ __forceinline__ void gload16(const bf16* g, bf16* l) {
    __builtin_amdgcn_global_load_lds((const __attribute__((address_space(1))) unsigned int*)g,
                                     (__attribute__((address_space(3))) unsigned int*)l, 16, 0, 0);
}

// ---------------------------------------------------------------- rope table
__global__ void k_rope_tab(float* __restrict__ cosT, float* __restrict__ sinT) {
    int idx = blockIdx.x * 256 + threadIdx.x;     // 4096*32 = 131072
    int t = idx >> 5, i = idx & 31;
    float freq = 1.0f / powf(10000.0f, (float)(2 * i) * (1.0f / 64.0f));
    float a = (float)t * freq;
    cosT[idx] = cosf(a);
    sinT[idx] = sinf(a);
}

// ---------------------------------------------------------------- x -> bf16
__global__ void k_convert_x(const float* __restrict__ X, bf16* __restrict__ Xb) {
    int i = (blockIdx.x * 256 + threadIdx.x) * 4;
    float4 v = *(const float4*)&X[i];
    union { bf16 h[4]; uint2 u; } p;
    p.h[0] = __float2bfloat16(v.x);
    p.h[1] = __float2bfloat16(v.y);
    p.h[2] = __float2bfloat16(v.z);
    p.h[3] = __float2bfloat16(v.w);
    *(uint2*)&Xb[i] = p.u;
}

// ------------------------------------------- W[k][n] -> Wt[n][k] (bf16)
__global__ void k_transpose(const float* __restrict__ W, bf16* __restrict__ Wt) {
    __shared__ float tile[32][33];
    int bx = blockIdx.x * 32;   // n
    int by = blockIdx.y * 32;   // k
    int tx = threadIdx.x;
    for (int i = threadIdx.y; i < 32; i += 8)
        tile[i][tx] = W[(size_t)(by + i) * DIM + bx + tx];
    __syncthreads();
    for (int i = threadIdx.y; i < 32; i += 8)
        Wt[(size_t)(bx + i) * DIM + by + tx] = __float2bfloat16(tile[tx][i]);
}

// ---------------------------------------------------------------- GEMM core (m97 structure)
__launch_bounds__(256, 2)
__global__ void k_gemm_proj(const bf16* __restrict__ A, const bf16* __restrict__ Bt,
                            float* __restrict__ C) {
    __shared__ alignas(16) bf16 As[128 * 32];
    __shared__ alignas(16) bf16 Bs[128 * 32];
    const int K = DIM;
    int tid = threadIdx.x;
    int lane = tid & 63, wave = tid >> 6;
    int wr = (wave >> 1) * 64, wc = (wave & 1) * 64;
    int m0 = blockIdx.y * 128, n0 = blockIdx.x * 128;
    int row = lane & 15, kk = (lane >> 4) * 8;
    int ch0 = wave * 128 + lane;
    int ch1 = ch0 + 64;
    int r0 = ch0 >> 2, c0e = (ch0 & 3) * 8;
    int r1 = ch1 >> 2, c1e = (ch1 & 3) * 8;
    bf16* ldsA0 = &As[wave * 1024];
    bf16* ldsA1 = &As[wave * 1024 + 512];
    bf16* ldsB0 = &Bs[wave * 1024];
    bf16* ldsB1 = &Bs[wave * 1024 + 512];
    f32x4 acc[4][4] = {};
    for (int k0 = 0; k0 < K; k0 += 32) {
        __syncthreads();
        gload16(&A[(size_t)(m0 + r0) * K + k0 + c0e], ldsA0);
        gload16(&A[(size_t)(m0 + r1) * K + k0 + c1e], ldsA1);
        gload16(&Bt[(size_t)(n0 + r0) * K + k0 + c0e], ldsB0);
        gload16(&Bt[(size_t)(n0 + r1) * K + k0 + c1e], ldsB1);
        __syncthreads();
        bf16x8 af[4], bfr[4];
#pragma unroll
        for (int mt = 0; mt < 4; ++mt) af[mt] = *(const bf16x8*)&As[(wr + mt * 16 + row) * 32 + kk];
#pragma unroll
        for (int nt = 0; nt < 4; ++nt) bfr[nt] = *(const bf16x8*)&Bs[(wc + nt * 16 + row) * 32 + kk];
#pragma unroll
        for (int mt = 0; mt < 4; ++mt)
#pragma unroll
            for (int nt = 0; nt < 4; ++nt)
                acc[mt][nt] = __builtin_amdgcn_mfma_f32_16x16x32_bf16(af[mt], bfr[nt], acc[mt][nt], 0, 0, 0);
    }
    int orow = (lane >> 4) * 4, ocol = lane & 15;
#pragma unroll
    for (int mt = 0; mt < 4; ++mt)
#pragma unroll
        for (int nt = 0; nt < 4; ++nt)
#pragma unroll
            for (int i = 0; i < 4; ++i)
                C[(size_t)(m0 + wr + mt * 16 + orow + i) * DIM + n0 + wc + nt * 16 + ocol] = acc[mt][nt][i];
}

// final GEMM: per-row-tile weight/bias select, fp32 out
__launch_bounds__(256, 2)
__global__ void k_gemm_out(const bf16* __restrict__ A, const bf16* __restrict__ Bt0,
                           const bf16* __restrict__ Bt1, const float* __restrict__ bias0,
                           const float* __restrict__ bias1, float* __restrict__ C) {
    __shared__ alignas(16) bf16 As[128 * 32];
    __shared__ alignas(16) bf16 Bs[128 * 32];
    const int K = DIM;
    int tid = threadIdx.x;
    int lane = tid & 63, wave = tid >> 6;
    int wr = (wave >> 1) * 64, wc = (wave & 1) * 64;
    int m0 = blockIdx.y * 128, n0 = blockIdx.x * 128;
    bool first = (m0 & (NSEQ - 1)) < MSEG;
    const bf16* Bt = first ? Bt0 : Bt1;
    const float* bias = first ? bias0 : bias1;
    int row = lane & 15, kk = (lane >> 4) * 8;
    int ch0 = wave * 128 + lane;
    int ch1 = ch0 + 64;
    int r0 = ch0 >> 2, c0e = (ch0 & 3) * 8;
    int r1 = ch1 >> 2, c1e = (ch1 & 3) * 8;
    bf16* ldsA0 = &As[wave * 1024];
    bf16* ldsA1 = &As[wave * 1024 + 512];
    bf16* ldsB0 = &Bs[wave * 1024];
    bf16* ldsB1 = &Bs[wave * 1024 + 512];
    f32x4 acc[4][4] = {};
    for (int k0 = 0; k0 < K; k0 += 32) {
        __syncthreads();
        gload16(&A[(size_t)(m0 + r0) * K + k0 + c0e], ldsA0);
        gload16(&A[(size_t)(m0 + r1) * K + k0 + c1e], ldsA1);
        gload16(&Bt[(size_t)(n0 + r0) * K + k0 + c0e], ldsB0);
        gload16(&Bt[(size_t)(n0 + r1) * K + k0 + c1e], ldsB1);
        __syncthreads();
        bf16x8 af[4], bfr[4];
#pragma unroll
        for (int mt = 0; mt < 4; ++mt) af[mt] = *(const bf16x8*)&As[(wr + mt * 16 + row) * 32 + kk];
#pragma unroll
        for (int nt = 0; nt < 4; ++nt) bfr[nt] = *(const bf16x8*)&Bs[(wc + nt * 16 + row) * 32 + kk];
#pragma unroll
        for (int mt = 0; mt < 4; ++mt)
#pragma unroll
            for (int nt = 0; nt < 4; ++nt)
                acc[mt][nt] = __builtin_amdgcn_mfma_f32_16x16x32_bf16(af[mt], bfr[nt], acc[mt][nt], 0, 0, 0);
    }
    int orow = (lane >> 4) * 4, ocol = lane & 15;
#pragma unroll
    for (int mt = 0; mt < 4; ++mt)
#pragma unroll
        for (int nt = 0; nt < 4; ++nt) {
            float bv = bias[n0 + wc + nt * 16 + ocol];
#pragma unroll
            for (int i = 0; i < 4; ++i)
                C[(size_t)(m0 + wr + mt * 16 + orow + i) * DIM + n0 + wc + nt * 16 + ocol] = acc[mt][nt][i] + bv;
        }
}

// ---------------------------------------------------------------- RoPE (Q)
__global__ void k_rope_q(const float* __restrict__ Y, const float* __restrict__ cosT,
                         const float* __restrict__ sinT, bf16* __restrict__ Qb) {
    int idx = blockIdx.x * 256 + threadIdx.x;   // ROWS*DIM/2 threads
    int e = idx & 31;
    int head = (idx >> 5) & 15;
    int rowg = idx >> 9;                        // 0..8191
    int t = rowg & (NSEQ - 1), bidx = rowg >> 12;
    float x1 = Y[(size_t)rowg * DIM + head * HD + e];
    float x2 = Y[(size_t)rowg * DIM + head * HD + e + 32];
    float cv = cosT[t * 32 + e], sv = sinT[t * 32 + e];
    float o1 = (x1 * cv - x2 * sv) * 0.125f;    // * d^-0.5
    float o2 = (x2 * cv + x1 * sv) * 0.125f;
    int c = bidx * NH + head;
    size_t base = ((size_t)c * NSEQ + t) * HD;
    Qb[base + e]      = __float2bfloat16(o1);
    Qb[base + e + 32] = __float2bfloat16(o2);
}

// ---------------------------------------------------------------- RoPE (KV) + transpose
__global__ void k_rope_kv(const float* __restrict__ Y, const float* __restrict__ cosT,
                          const float* __restrict__ sinT, bf16* __restrict__ KVb,
                          bf16* __restrict__ KVt) {
    int idx = blockIdx.x * 256 + threadIdx.x;
    int e = idx & 31;
    int head = (idx >> 5) & 15;
    int rowg = idx >> 9;
    int t = rowg & (NSEQ - 1), bidx = rowg >> 12;
    float x1 = Y[(size_t)rowg * DIM + head * HD + e];
    float x2 = Y[(size_t)rowg * DIM + head * HD + e + 32];
    float cv = cosT[t * 32 + e], sv = sinT[t * 32 + e];
    float o1 = x1 * cv - x2 * sv;
    float o2 = x2 * cv + x1 * sv;
    int c = bidx * NH + head;
    size_t base = ((size_t)c * NSEQ + t) * HD;
    KVb[base + e]      = __float2bfloat16(o1);
    KVb[base + e + 32] = __float2bfloat16(o2);
    KVt[((size_t)c * HD + e) * NSEQ + t]      = __float2bfloat16(o1);
    KVt[((size_t)c * HD + e + 32) * NSEQ + t] = __float2bfloat16(o2);
}

// ---------------------------------------------------------------- attention (swapped-QK 32x32)
// grid: 1024 blocks; XCD-local channels, heavy-first (LPT) block order within XCD chunk
__launch_bounds__(256, 2)
__global__ void k_attn(const bf16* __restrict__ Qb, const bf16* __restrict__ KVb,
                       const bf16* __restrict__ KVt, bf16* __restrict__ Ob) {
    int lane = threadIdx.x & 63, wave = threadIdx.x >> 6;
    int hi = lane >> 5, lq = lane & 31;
    // id -> (xcd, rank); XCD owns channels 4*xcd..4*xcd+3; rank>>2 = heaviness order
    int id = blockIdx.x;
    int xcd = id & 7, rank = id >> 3;           // rank 0..127
    int c = xcd * 4 + (rank & 3);
    int hr = rank >> 2;                         // 0..31, heavy-first
    int bx, seg;
    if (hr < 28) { bx = 3 - hr / 7; seg = 1 + hr % 7; }
    else         { seg = 0; bx = 31 - hr; }
    int i0 = bx * 128 + wave * 32;              // q-row offset within segment
    int bidx = c >> 4, head = c & 15;
    int tq = seg * MSEG + i0 + lq;
    const bf16* qptr = &Qb[((size_t)c * NSEQ + tq) * HD + hi * 8];
    bf16x8 qf[4];
#pragma unroll
    for (int dc = 0; dc < 4; ++dc) qf[dc] = *(const bf16x8*)&qptr[dc * 16];
    f32x16 o0 = {}, o1 = {};
    float mrun = -FLT_MAX, lrun = 0.f;
    int kvbase = (seg == 0) ? 0 : (seg - 1) * MSEG;
    int cstart = (seg == 0) ? 0 : MSEG;         // cols >= cstart are causal vs local row
    int cend = cstart + i0 + 32;

    const bf16* kbase = &KVb[((size_t)c * NSEQ + kvbase + lq) * HD + hi * 8];
    const bf16* vbase = &KVt[((size_t)c * HD + lq) * NSEQ + kvbase + hi * 8];

    for (int c0 = 0; c0 < cend; c0 += 32) {
        // ---- K / V^T fragments (direct loads; L2-resident via XCD locality)
        const bf16* kp = kbase + (size_t)c0 * HD;
        const bf16* vp = vbase + c0;
        bf16x8 kf0 = *(const bf16x8*)&kp[0];
        bf16x8 kf1 = *(const bf16x8*)&kp[16];
        bf16x8 kf2 = *(const bf16x8*)&kp[32];
        bf16x8 kf3 = *(const bf16x8*)&kp[48];
        bf16x8 vf0 = *(const bf16x8*)&vp[0];
        bf16x8 vf1 = *(const bf16x8*)&vp[16];
        bf16x8 vf2 = *(const bf16x8*)&vp[(size_t)32 * NSEQ];
        bf16x8 vf3 = *(const bf16x8*)&vp[(size_t)32 * NSEQ + 16];
        // ---- S^T[kv][q] : lane holds q=lq, kv = (r&3)+8*(r>>2)+4*hi
        f32x16 s = {};
        __builtin_amdgcn_s_setprio(1);
        s = __builtin_amdgcn_mfma_f32_32x32x16_bf16(kf0, qf[0], s, 0, 0, 0);
        s = __builtin_amdgcn_mfma_f32_32x32x16_bf16(kf1, qf[1], s, 0, 0, 0);
        s = __builtin_amdgcn_mfma_f32_32x32x16_bf16(kf2, qf[2], s, 0, 0, 0);
        s = __builtin_amdgcn_mfma_f32_32x32x16_bf16(kf3, qf[3], s, 0, 0, 0);
        __builtin_amdgcn_s_setprio(0);
        if (c0 + 31 >= cstart && c0 + 31 - cstart > i0) {
#pragma unroll
            for (int r = 0; r < 16; ++r) {
                int kvg = c0 + ((r & 3) + 8 * (r >> 2) + 4 * hi);
                if (kvg >= cstart && kvg - cstart > i0 + lq) s[r] = -FLT_MAX;
            }
        }
        // ---- online softmax, defer-max (T13): rescale only if max grew by >8
        float t8[8], t4[4];
#pragma unroll
        for (int r = 0; r < 8; ++r) t8[r] = fmaxf(s[2 * r], s[2 * r + 1]);
#pragma unroll
        for (int r = 0; r < 4; ++r) t4[r] = fmaxf(t8[2 * r], t8[2 * r + 1]);
        float vmax = fmaxf(fmaxf(t4[0], t4[1]), fmaxf(t4[2], t4[3]));
        vmax = fmaxf(vmax, __shfl_xor(vmax, 32));
        if (__any(vmax > mrun + 8.0f)) {
            float nm = fmaxf(mrun, vmax);
            float al = __expf(mrun - nm);
#pragma unroll
            for (int r = 0; r < 16; ++r) { o0[r] *= al; o1[r] *= al; }
            lrun *= al;
            mrun = nm;
        }
        float p[16];
#pragma unroll
        for (int r = 0; r < 16; ++r) p[r] = __expf(s[r] - mrun);
        float a8[8], a4[4];
#pragma unroll
        for (int r = 0; r < 8; ++r) a8[r] = p[2 * r] + p[2 * r + 1];
#pragma unroll
        for (int r = 0; r < 4; ++r) a4[r] = a8[2 * r] + a8[2 * r + 1];
        lrun += (a4[0] + a4[1]) + (a4[2] + a4[3]);   // per-lane partial; merged at end
        // ---- P^T -> B-fragment: pack pairs, exchange only the needed half (4 shfl)
        unsigned pk[8];
#pragma unroll
        for (int k = 0; k < 8; ++k) {
            union { bf16 h[2]; unsigned u; } cv;
            cv.h[0] = __float2bfloat16(p[2 * k]);
            cv.h[1] = __float2bfloat16(p[2 * k + 1]);
            pk[k] = cv.u;
        }
        unsigned u0 = hi ? pk[0] : pk[2];
        unsigned u1 = hi ? pk[1] : pk[3];
        unsigned u2 = hi ? pk[4] : pk[6];
        unsigned u3 = hi ? pk[5] : pk[7];
        unsigned r0 = (unsigned)__shfl_xor((int)u0, 32);
        unsigned r1 = (unsigned)__shfl_xor((int)u1, 32);
        unsigned r2 = (unsigned)__shfl_xor((int)u2, 32);
        unsigned r3 = (unsigned)__shfl_xor((int)u3, 32);
        union { unsigned u[4]; bf16x8 v; } b0, b1;
        if (hi == 0) {
            b0.u[0] = pk[0]; b0.u[1] = pk[1]; b0.u[2] = r0; b0.u[3] = r1;
            b1.u[0] = pk[4]; b1.u[1] = pk[5]; b1.u[2] = r2; b1.u[3] = r3;
        } else {
            b0.u[0] = r0; b0.u[1] = r1; b0.u[2] = pk[2]; b0.u[3] = pk[3];
            b1.u[0] = r2; b1.u[1] = r3; b1.u[2] = pk[6]; b1.u[3] = pk[7];
        }
        // ---- O^T[d][q] += V^T P^T
        __builtin_amdgcn_s_setprio(1);
        o0 = __builtin_amdgcn_mfma_f32_32x32x16_bf16(vf0, b0.v, o0, 0, 0, 0);
        o0 = __builtin_amdgcn_mfma_f32_32x32x16_bf16(vf1, b1.v, o0, 0, 0, 0);
        o1 = __builtin_amdgcn_mfma_f32_32x32x16_bf16(vf2, b0.v, o1, 0, 0, 0);
        o1 = __builtin_amdgcn_mfma_f32_32x32x16_bf16(vf3, b1.v, o1, 0, 0, 0);
        __builtin_amdgcn_s_setprio(0);
    }
    lrun += __shfl_xor(lrun, 32);
    float inv = 1.0f / lrun;
    size_t obase = ((size_t)bidx * NSEQ + tq) * DIM + head * HD;
#pragma unroll
    for (int dt = 0; dt < 2; ++dt)
#pragma unroll
        for (int a = 0; a < 4; ++a) {
            union { bf16 h[4]; uint2 u; } pkd;
            const f32x16& ov = dt ? o1 : o0;
#pragma unroll
            for (int i = 0; i < 4; ++i) pkd.h[i] = __float2bfloat16(ov[4 * a + i] * inv);
            *(uint2*)&Ob[obase + dt * 32 + 8 * a + 4 * hi] = pkd.u;
        }
}

// ---------------------------------------------------------------- launch
extern "C" void kernel_launch(void* const* d_in, const int* in_sizes, int n_in,
                              void* d_out, int out_size, void* d_ws, size_t ws_size,
                              hipStream_t stream) {
    const float* x   = (const float*)d_in[0];
    const float* Wq  = (const float*)d_in[1];
    const float* Wkv = (const float*)d_in[2];
    const float* Wo  = (const float*)d_in[3];
    const float* bo  = (const float*)d_in[4];
    const float* Wo0 = (const float*)d_in[5];
    const float* bo0 = (const float*)d_in[6];
    float* out = (float*)d_out;

    char* ws = (char*)d_ws;
    size_t off = 0;
    auto alloc = [&](size_t bytes) { void* p = ws + off; off += (bytes + 255) & ~(size_t)255; return p; };
    float* cosT = (float*)alloc((size_t)NSEQ * 32 * 4);
    float* sinT = (float*)alloc((size_t)NSEQ * 32 * 4);
    bf16* Xb    = (bf16*)alloc((size_t)ROWS * DIM * 2);
    bf16* WqT   = (bf16*)alloc((size_t)DIM * DIM * 2);
    bf16* WkvT  = (bf16*)alloc((size_t)DIM * DIM * 2);
    bf16* WoT   = (bf16*)alloc((size_t)DIM * DIM * 2);
    bf16* Wo0T  = (bf16*)alloc((size_t)DIM * DIM * 2);
    float* Y    = (float*)alloc((size_t)ROWS * DIM * 4);
    bf16* Qb    = (bf16*)alloc((size_t)NC * NSEQ * HD * 2);
    bf16* KVb   = (bf16*)alloc((size_t)NC * NSEQ * HD * 2);
    bf16* KVt   = (bf16*)alloc((size_t)NC * HD * NSEQ * 2);
    bf16* Ob    = (bf16*)alloc((size_t)ROWS * DIM * 2);

    hipLaunchKernelGGL(k_rope_tab, dim3(NSEQ * 32 / 256), dim3(256), 0, stream, cosT, sinT);
    hipLaunchKernelGGL(k_convert_x, dim3(ROWS * DIM / 4 / 256), dim3(256), 0, stream, x, Xb);
    hipLaunchKernelGGL(k_transpose, dim3(32, 32), dim3(32, 8), 0, stream, Wq, WqT);
    hipLaunchKernelGGL(k_transpose, dim3(32, 32), dim3(32, 8), 0, stream, Wkv, WkvT);
    hipLaunchKernelGGL(k_transpose, dim3(32, 32), dim3(32, 8), 0, stream, Wo, WoT);
    hipLaunchKernelGGL(k_transpose, dim3(32, 32), dim3(32, 8), 0, stream, Wo0, Wo0T);

    hipLaunchKernelGGL(k_gemm_proj, dim3(8, 64), dim3(256), 0, stream, Xb, WqT, Y);
    hipLaunchKernelGGL(k_rope_q, dim3(ROWS * DIM / 2 / 256), dim3(256), 0, stream, Y, cosT, sinT, Qb);
    hipLaunchKernelGGL(k_gemm_proj, dim3(8, 64), dim3(256), 0, stream, Xb, WkvT, Y);
    hipLaunchKernelGGL(k_rope_kv, dim3(ROWS * DIM / 2 / 256), dim3(256), 0, stream, Y, cosT, sinT, KVb, KVt);

    hipLaunchKernelGGL(k_attn, dim3(1024), dim3(256), 0, stream, Qb, KVb, KVt, Ob);

    hipLaunchKernelGGL(k_gemm_out, dim3(8, 64), dim3(256), 0, stream, Ob, Wo0T, WoT, bo0, bo, out);
}

// Round 5
// 209.659 us; speedup vs baseline: 1.4069x; 1.2567x over previous
//
#include <hip/hip_runtime.h>
#include <hip/hip_bf16.h>
#include <float.h>

using bf16 = __hip_bfloat16;
typedef __attribute__((ext_vector_type(8))) short bf16x8;
typedef __attribute__((ext_vector_type(4))) float f32x4;
typedef __attribute__((ext_vector_type(16))) float f32x16;

#define DIM   1024
#define NSEQ  4096
#define BATCH 2
#define NH    16
#define HD    64
#define NSEG  8
#define MSEG  512
#define ROWS  (BATCH*NSEQ)   // 8192
#define NC    (BATCH*NH)     // 32

__device__ __forceinline__ void gload16(const bf16* g, bf16* l) {
    __builtin_amdgcn_global_load_lds((const __attribute__((address_space(1))) unsigned int*)g,
                                     (__attribute__((address_space(3))) unsigned int*)l, 16, 0, 0);
}

// ---------------------------------------------------------------- rope table
__global__ void k_rope_tab(float* __restrict__ cosT, float* __restrict__ sinT) {
    int idx = blockIdx.x * 256 + threadIdx.x;     // 4096*32 = 131072
    int t = idx >> 5, i = idx & 31;
    float freq = 1.0f / powf(10000.0f, (float)(2 * i) * (1.0f / 64.0f));
    float a = (float)t * freq;
    cosT[idx] = cosf(a);
    sinT[idx] = sinf(a);
}

// ---------------------------------------------------------------- x -> bf16
__global__ void k_convert_x(const float* __restrict__ X, bf16* __restrict__ Xb) {
    int i = (blockIdx.x * 256 + threadIdx.x) * 4;
    float4 v = *(const float4*)&X[i];
    union { bf16 h[4]; uint2 u; } p;
    p.h[0] = __float2bfloat16(v.x);
    p.h[1] = __float2bfloat16(v.y);
    p.h[2] = __float2bfloat16(v.z);
    p.h[3] = __float2bfloat16(v.w);
    *(uint2*)&Xb[i] = p.u;
}

// ------------------------------------------- W[k][n] -> Wt[n][k] (bf16)
__global__ void k_transpose(const float* __restrict__ W, bf16* __restrict__ Wt) {
    __shared__ float tile[32][33];
    int bx = blockIdx.x * 32;   // n
    int by = blockIdx.y * 32;   // k
    int tx = threadIdx.x;
    for (int i = threadIdx.y; i < 32; i += 8)
        tile[i][tx] = W[(size_t)(by + i) * DIM + bx + tx];
    __syncthreads();
    for (int i = threadIdx.y; i < 32; i += 8)
        Wt[(size_t)(bx + i) * DIM + by + tx] = __float2bfloat16(tile[tx][i]);
}

// ------------------------------------- merged Q+KV projection GEMM, 2-phase dbuf
// virtual N=2048: bxx<8 -> Yq=Xb*WqT^T (bf16), else Ykv=Xb*WkvT^T (bf16)
__launch_bounds__(256, 4)
__global__ void k_gemm_qkv(const bf16* __restrict__ A, const bf16* __restrict__ Bq,
                           const bf16* __restrict__ Bkv, bf16* __restrict__ Yq,
                           bf16* __restrict__ Ykv) {
    __shared__ alignas(16) bf16 As[2][128 * 32];
    __shared__ alignas(16) bf16 Bs[2][128 * 32];
    const int K = DIM;
    int tid = threadIdx.x;
    int lane = tid & 63, wave = tid >> 6;
    int wr = (wave >> 1) * 64, wc = (wave & 1) * 64;
    // XCD-chunked swizzle over 1024 blocks: xcd owns 8 m-rows x 16 n-cols
    int id = blockIdx.x;
    int xcd = id & 7, rank = id >> 3;      // rank 0..127
    int by = xcd * 8 + (rank >> 4);        // 0..63
    int bxx = rank & 15;                   // 0..15 (virtual n block)
    int m0 = by * 128;
    const bf16* Bt = (bxx < 8) ? Bq : Bkv;
    bf16* C = (bxx < 8) ? Yq : Ykv;
    int n0 = (bxx & 7) * 128;
    int row = lane & 15, kk = (lane >> 4) * 8;
    int ch0 = wave * 128 + lane, ch1 = ch0 + 64;
    int r0 = ch0 >> 2, c0e = (ch0 & 3) * 8;
    int r1 = ch1 >> 2, c1e = (ch1 & 3) * 8;
    f32x4 acc[4][4] = {};
    // prologue stage into buf 0
    gload16(&A[(size_t)(m0 + r0) * K + c0e], &As[0][wave * 1024]);
    gload16(&A[(size_t)(m0 + r1) * K + c1e], &As[0][wave * 1024 + 512]);
    gload16(&Bt[(size_t)(n0 + r0) * K + c0e], &Bs[0][wave * 1024]);
    gload16(&Bt[(size_t)(n0 + r1) * K + c1e], &Bs[0][wave * 1024 + 512]);
    __syncthreads();
    int cur = 0;
    for (int k0 = 0; k0 < K; k0 += 32) {
        int nxt = cur ^ 1;
        if (k0 + 32 < K) {
            gload16(&A[(size_t)(m0 + r0) * K + k0 + 32 + c0e], &As[nxt][wave * 1024]);
            gload16(&A[(size_t)(m0 + r1) * K + k0 + 32 + c1e], &As[nxt][wave * 1024 + 512]);
            gload16(&Bt[(size_t)(n0 + r0) * K + k0 + 32 + c0e], &Bs[nxt][wave * 1024]);
            gload16(&Bt[(size_t)(n0 + r1) * K + k0 + 32 + c1e], &Bs[nxt][wave * 1024 + 512]);
        }
        bf16x8 af[4], bfr[4];
#pragma unroll
        for (int mt = 0; mt < 4; ++mt) af[mt] = *(const bf16x8*)&As[cur][(wr + mt * 16 + row) * 32 + kk];
#pragma unroll
        for (int nt = 0; nt < 4; ++nt) bfr[nt] = *(const bf16x8*)&Bs[cur][(wc + nt * 16 + row) * 32 + kk];
#pragma unroll
        for (int mt = 0; mt < 4; ++mt)
#pragma unroll
            for (int nt = 0; nt < 4; ++nt)
                acc[mt][nt] = __builtin_amdgcn_mfma_f32_16x16x32_bf16(af[mt], bfr[nt], acc[mt][nt], 0, 0, 0);
        __syncthreads();
        cur = nxt;
    }
    int orow = (lane >> 4) * 4, ocol = lane & 15;
#pragma unroll
    for (int mt = 0; mt < 4; ++mt)
#pragma unroll
        for (int nt = 0; nt < 4; ++nt)
#pragma unroll
            for (int i = 0; i < 4; ++i)
                C[(size_t)(m0 + wr + mt * 16 + orow + i) * DIM + n0 + wc + nt * 16 + ocol] =
                    __float2bfloat16(acc[mt][nt][i]);
}

// final GEMM: 2-phase dbuf, XCD swizzle, per-row-tile weight/bias select, fp32 out
__launch_bounds__(256, 2)
__global__ void k_gemm_out(const bf16* __restrict__ A, const bf16* __restrict__ Bt0,
                           const bf16* __restrict__ Bt1, const float* __restrict__ bias0,
                           const float* __restrict__ bias1, float* __restrict__ C) {
    __shared__ alignas(16) bf16 As[2][128 * 32];
    __shared__ alignas(16) bf16 Bs[2][128 * 32];
    const int K = DIM;
    int tid = threadIdx.x;
    int lane = tid & 63, wave = tid >> 6;
    int wr = (wave >> 1) * 64, wc = (wave & 1) * 64;
    int id = blockIdx.x;                   // 512 blocks
    int xcd = id & 7, rank = id >> 3;      // 0..63
    int by = xcd * 8 + (rank >> 3);        // 0..63
    int bx = rank & 7;
    int m0 = by * 128, n0 = bx * 128;
    bool first = (m0 & (NSEQ - 1)) < MSEG;
    const bf16* Bt = first ? Bt0 : Bt1;
    const float* bias = first ? bias0 : bias1;
    int row = lane & 15, kk = (lane >> 4) * 8;
    int ch0 = wave * 128 + lane, ch1 = ch0 + 64;
    int r0 = ch0 >> 2, c0e = (ch0 & 3) * 8;
    int r1 = ch1 >> 2, c1e = (ch1 & 3) * 8;
    f32x4 acc[4][4] = {};
    gload16(&A[(size_t)(m0 + r0) * K + c0e], &As[0][wave * 1024]);
    gload16(&A[(size_t)(m0 + r1) * K + c1e], &As[0][wave * 1024 + 512]);
    gload16(&Bt[(size_t)(n0 + r0) * K + c0e], &Bs[0][wave * 1024]);
    gload16(&Bt[(size_t)(n0 + r1) * K + c1e], &Bs[0][wave * 1024 + 512]);
    __syncthreads();
    int cur = 0;
    for (int k0 = 0; k0 < K; k0 += 32) {
        int nxt = cur ^ 1;
        if (k0 + 32 < K) {
            gload16(&A[(size_t)(m0 + r0) * K + k0 + 32 + c0e], &As[nxt][wave * 1024]);
            gload16(&A[(size_t)(m0 + r1) * K + k0 + 32 + c1e], &As[nxt][wave * 1024 + 512]);
            gload16(&Bt[(size_t)(n0 + r0) * K + k0 + 32 + c0e], &Bs[nxt][wave * 1024]);
            gload16(&Bt[(size_t)(n0 + r1) * K + k0 + 32 + c1e], &Bs[nxt][wave * 1024 + 512]);
        }
        bf16x8 af[4], bfr[4];
#pragma unroll
        for (int mt = 0; mt < 4; ++mt) af[mt] = *(const bf16x8*)&As[cur][(wr + mt * 16 + row) * 32 + kk];
#pragma unroll
        for (int nt = 0; nt < 4; ++nt) bfr[nt] = *(const bf16x8*)&Bs[cur][(wc + nt * 16 + row) * 32 + kk];
#pragma unroll
        for (int mt = 0; mt < 4; ++mt)
#pragma unroll
            for (int nt = 0; nt < 4; ++nt)
                acc[mt][nt] = __builtin_amdgcn_mfma_f32_16x16x32_bf16(af[mt], bfr[nt], acc[mt][nt], 0, 0, 0);
        __syncthreads();
        cur = nxt;
    }
    int orow = (lane >> 4) * 4, ocol = lane & 15;
#pragma unroll
    for (int mt = 0; mt < 4; ++mt)
#pragma unroll
        for (int nt = 0; nt < 4; ++nt) {
            float bv = bias[n0 + wc + nt * 16 + ocol];
#pragma unroll
            for (int i = 0; i < 4; ++i)
                C[(size_t)(m0 + wr + mt * 16 + orow + i) * DIM + n0 + wc + nt * 16 + ocol] = acc[mt][nt][i] + bv;
        }
}

// ---------------------------------------------------------------- RoPE (Q) from bf16 Y
__global__ void k_rope_q(const bf16* __restrict__ Y, const float* __restrict__ cosT,
                         const float* __restrict__ sinT, bf16* __restrict__ Qb) {
    int idx = blockIdx.x * 256 + threadIdx.x;   // ROWS*DIM/2 threads
    int e = idx & 31;
    int head = (idx >> 5) & 15;
    int rowg = idx >> 9;                        // 0..8191
    int t = rowg & (NSEQ - 1), bidx = rowg >> 12;
    float x1 = __bfloat162float(Y[(size_t)rowg * DIM + head * HD + e]);
    float x2 = __bfloat162float(Y[(size_t)rowg * DIM + head * HD + e + 32]);
    float cv = cosT[t * 32 + e], sv = sinT[t * 32 + e];
    float o1 = (x1 * cv - x2 * sv) * 0.125f;    // * d^-0.5
    float o2 = (x2 * cv + x1 * sv) * 0.125f;
    int c = bidx * NH + head;
    size_t base = ((size_t)c * NSEQ + t) * HD;
    Qb[base + e]      = __float2bfloat16(o1);
    Qb[base + e + 32] = __float2bfloat16(o2);
}

// --------------------------- RoPE (KV) + LDS-tiled transpose (coalesced KVt writes)
// grid: (16 t-tiles, 32 channels); block 256
__global__ void k_rope_kv(const bf16* __restrict__ Y, const float* __restrict__ cosT,
                          const float* __restrict__ sinT, bf16* __restrict__ KVb,
                          bf16* __restrict__ KVt) {
    __shared__ bf16 T[64][264];
    int c = blockIdx.y, tt = blockIdx.x;
    int bidx = c >> 4, head = c & 15;
    int t0 = tt * 256;
    int e = threadIdx.x & 31;        // 0..31
    int tl = threadIdx.x >> 5;       // 0..7
    for (int it = 0; it < 32; ++it) {
        int tloc = it * 8 + tl;
        int t = t0 + tloc;
        int rowg = bidx * NSEQ + t;
        float x1 = __bfloat162float(Y[(size_t)rowg * DIM + head * HD + e]);
        float x2 = __bfloat162float(Y[(size_t)rowg * DIM + head * HD + e + 32]);
        float cv = cosT[t * 32 + e], sv = sinT[t * 32 + e];
        bf16 b1 = __float2bfloat16(x1 * cv - x2 * sv);
        bf16 b2 = __float2bfloat16(x2 * cv + x1 * sv);
        size_t base = ((size_t)c * NSEQ + t) * HD;
        KVb[base + e]      = b1;
        KVb[base + e + 32] = b2;
        T[e][tloc]      = b1;
        T[e + 32][tloc] = b2;
    }
    __syncthreads();
    // write KVt[c][d][t0..t0+255] as coalesced 16B stores (quad of lanes = 64B contiguous)
    int d = threadIdx.x >> 2, part = threadIdx.x & 3;
    size_t trow = ((size_t)c * HD + d) * NSEQ + t0;
#pragma unroll
    for (int k = 0; k < 8; ++k) {
        int col = k * 32 + part * 8;
        union { bf16 h[8]; uint4 u; } pk;
#pragma unroll
        for (int j = 0; j < 8; ++j) pk.h[j] = T[d][col + j];
        *(uint4*)&KVt[trow + col] = pk.u;
    }
}

// ---------------------------------------------------------------- attention (swapped-QK 32x32)
// 64 kv per iteration as two independent 32-subtiles (2x MFMA ILP); LPT + XCD-local order
__launch_bounds__(256, 3)
__global__ void k_attn(const bf16* __restrict__ Qb, const bf16* __restrict__ KVb,
                       const bf16* __restrict__ KVt, bf16* __restrict__ Ob) {
    int lane = threadIdx.x & 63, wave = threadIdx.x >> 6;
    int hi = lane >> 5, lq = lane & 31;
    int id = blockIdx.x;
    int xcd = id & 7, rank = id >> 3;           // rank 0..127
    int c = xcd * 4 + (rank & 3);
    int hr = rank >> 2;                         // 0..31, heavy-first
    int bx, seg;
    if (hr < 28) { bx = 3 - hr / 7; seg = 1 + hr % 7; }
    else         { seg = 0; bx = 31 - hr; }
    int i0 = bx * 128 + wave * 32;              // q-row offset within segment
    int bidx = c >> 4, head = c & 15;
    int tq = seg * MSEG + i0 + lq;
    const bf16* qptr = &Qb[((size_t)c * NSEQ + tq) * HD + hi * 8];
    bf16x8 qf[4];
#pragma unroll
    for (int dc = 0; dc < 4; ++dc) qf[dc] = *(const bf16x8*)&qptr[dc * 16];
    f32x16 o0 = {}, o1 = {};
    float mrun = -FLT_MAX, lrun = 0.f;
    int kvbase = (seg == 0) ? 0 : (seg - 1) * MSEG;
    int cstart = (seg == 0) ? 0 : MSEG;
    int cend = cstart + i0 + 32;

    const bf16* kbase = &KVb[((size_t)c * NSEQ + kvbase + lq) * HD + hi * 8];
    const bf16* vbase = &KVt[((size_t)c * HD + lq) * NSEQ + kvbase + hi * 8];

    for (int c0 = 0; c0 < cend; c0 += 64) {
        int c0B = c0 + 32;
        // ---- K fragments for both subtiles
        const bf16* kpA = kbase + (size_t)c0 * HD;
        const bf16* kpB = kbase + (size_t)c0B * HD;
        bf16x8 kA0 = *(const bf16x8*)&kpA[0];
        bf16x8 kA1 = *(const bf16x8*)&kpA[16];
        bf16x8 kA2 = *(const bf16x8*)&kpA[32];
        bf16x8 kA3 = *(const bf16x8*)&kpA[48];
        bf16x8 kB0 = *(const bf16x8*)&kpB[0];
        bf16x8 kB1 = *(const bf16x8*)&kpB[16];
        bf16x8 kB2 = *(const bf16x8*)&kpB[32];
        bf16x8 kB3 = *(const bf16x8*)&kpB[48];
        // ---- two independent QK chains
        f32x16 sA = {}, sB = {};
        __builtin_amdgcn_s_setprio(1);
        sA = __builtin_amdgcn_mfma_f32_32x32x16_bf16(kA0, qf[0], sA, 0, 0, 0);
        sB = __builtin_amdgcn_mfma_f32_32x32x16_bf16(kB0, qf[0], sB, 0, 0, 0);
        sA = __builtin_amdgcn_mfma_f32_32x32x16_bf16(kA1, qf[1], sA, 0, 0, 0);
        sB = __builtin_amdgcn_mfma_f32_32x32x16_bf16(kB1, qf[1], sB, 0, 0, 0);
        sA = __builtin_amdgcn_mfma_f32_32x32x16_bf16(kA2, qf[2], sA, 0, 0, 0);
        sB = __builtin_amdgcn_mfma_f32_32x32x16_bf16(kB2, qf[2], sB, 0, 0, 0);
        sA = __builtin_amdgcn_mfma_f32_32x32x16_bf16(kA3, qf[3], sA, 0, 0, 0);
        sB = __builtin_amdgcn_mfma_f32_32x32x16_bf16(kB3, qf[3], sB, 0, 0, 0);
        __builtin_amdgcn_s_setprio(0);
        // ---- masks (per subtile); tail subtile fully masked automatically
        if (c0 + 31 >= cstart && c0 + 31 - cstart > i0) {
#pragma unroll
            for (int r = 0; r < 16; ++r) {
                int kvg = c0 + ((r & 3) + 8 * (r >> 2) + 4 * hi);
                if (kvg >= cstart && kvg - cstart > i0 + lq) sA[r] = -FLT_MAX;
            }
        }
        if (c0B + 31 >= cstart && c0B + 31 - cstart > i0) {
#pragma unroll
            for (int r = 0; r < 16; ++r) {
                int kvg = c0B + ((r & 3) + 8 * (r >> 2) + 4 * hi);
                if (kvg >= cstart && kvg - cstart > i0 + lq) sB[r] = -FLT_MAX;
            }
        }
        // ---- combined online softmax with defer-max
        float m16[16];
#pragma unroll
        for (int r = 0; r < 16; ++r) m16[r] = fmaxf(sA[r], sB[r]);
        float m8[8], m4[4];
#pragma unroll
        for (int r = 0; r < 8; ++r) m8[r] = fmaxf(m16[2 * r], m16[2 * r + 1]);
#pragma unroll
        for (int r = 0; r < 4; ++r) m4[r] = fmaxf(m8[2 * r], m8[2 * r + 1]);
        float vmax = fmaxf(fmaxf(m4[0], m4[1]), fmaxf(m4[2], m4[3]));
        vmax = fmaxf(vmax, __shfl_xor(vmax, 32));
        if (__any(vmax > mrun + 8.0f)) {
            float nm = fmaxf(mrun, vmax);
            float al = __expf(mrun - nm);
#pragma unroll
            for (int r = 0; r < 16; ++r) { o0[r] *= al; o1[r] *= al; }
            lrun *= al;
            mrun = nm;
        }
        float pA[16], pB[16];
#pragma unroll
        for (int r = 0; r < 16; ++r) pA[r] = __expf(sA[r] - mrun);
#pragma unroll
        for (int r = 0; r < 16; ++r) pB[r] = __expf(sB[r] - mrun);
        float a16[16], a8[8], a4[4];
#pragma unroll
        for (int r = 0; r < 16; ++r) a16[r] = pA[r] + pB[r];
#pragma unroll
        for (int r = 0; r < 8; ++r) a8[r] = a16[2 * r] + a16[2 * r + 1];
#pragma unroll
        for (int r = 0; r < 4; ++r) a4[r] = a8[2 * r] + a8[2 * r + 1];
        lrun += (a4[0] + a4[1]) + (a4[2] + a4[3]);
        // ---- pack subtile A -> b0,b1
        unsigned pk[8];
#pragma unroll
        for (int k = 0; k < 8; ++k) {
            union { bf16 h[2]; unsigned u; } cv;
            cv.h[0] = __float2bfloat16(pA[2 * k]);
            cv.h[1] = __float2bfloat16(pA[2 * k + 1]);
            pk[k] = cv.u;
        }
        unsigned u0 = hi ? pk[0] : pk[2];
        unsigned u1 = hi ? pk[1] : pk[3];
        unsigned u2 = hi ? pk[4] : pk[6];
        unsigned u3 = hi ? pk[5] : pk[7];
        unsigned w0 = (unsigned)__shfl_xor((int)u0, 32);
        unsigned w1 = (unsigned)__shfl_xor((int)u1, 32);
        unsigned w2 = (unsigned)__shfl_xor((int)u2, 32);
        unsigned w3 = (unsigned)__shfl_xor((int)u3, 32);
        union { unsigned u[4]; bf16x8 v; } b0, b1;
        if (hi == 0) {
            b0.u[0] = pk[0]; b0.u[1] = pk[1]; b0.u[2] = w0; b0.u[3] = w1;
            b1.u[0] = pk[4]; b1.u[1] = pk[5]; b1.u[2] = w2; b1.u[3] = w3;
        } else {
            b0.u[0] = w0; b0.u[1] = w1; b0.u[2] = pk[2]; b0.u[3] = pk[3];
            b1.u[0] = w2; b1.u[1] = w3; b1.u[2] = pk[6]; b1.u[3] = pk[7];
        }
        // ---- pack subtile B -> b2,b3
#pragma unroll
        for (int k = 0; k < 8; ++k) {
            union { bf16 h[2]; unsigned u; } cv;
            cv.h[0] = __float2bfloat16(pB[2 * k]);
            cv.h[1] = __float2bfloat16(pB[2 * k + 1]);
            pk[k] = cv.u;
        }
        u0 = hi ? pk[0] : pk[2];
        u1 = hi ? pk[1] : pk[3];
        u2 = hi ? pk[4] : pk[6];
        u3 = hi ? pk[5] : pk[7];
        w0 = (unsigned)__shfl_xor((int)u0, 32);
        w1 = (unsigned)__shfl_xor((int)u1, 32);
        w2 = (unsigned)__shfl_xor((int)u2, 32);
        w3 = (unsigned)__shfl_xor((int)u3, 32);
        union { unsigned u[4]; bf16x8 v; } b2, b3;
        if (hi == 0) {
            b2.u[0] = pk[0]; b2.u[1] = pk[1]; b2.u[2] = w0; b2.u[3] = w1;
            b3.u[0] = pk[4]; b3.u[1] = pk[5]; b3.u[2] = w2; b3.u[3] = w3;
        } else {
            b2.u[0] = w0; b2.u[1] = w1; b2.u[2] = pk[2]; b2.u[3] = pk[3];
            b3.u[0] = w2; b3.u[1] = w3; b3.u[2] = pk[6]; b3.u[3] = pk[7];
        }
        // ---- V^T fragments + PV
        const bf16* vpA = vbase + c0;
        const bf16* vpB = vbase + c0B;
        bf16x8 vA0 = *(const bf16x8*)&vpA[0];
        bf16x8 vA1 = *(const bf16x8*)&vpA[16];
        bf16x8 vA2 = *(const bf16x8*)&vpA[(size_t)32 * NSEQ];
        bf16x8 vA3 = *(const bf16x8*)&vpA[(size_t)32 * NSEQ + 16];
        bf16x8 vB0 = *(const bf16x8*)&vpB[0];
        bf16x8 vB1 = *(const bf16x8*)&vpB[16];
        bf16x8 vB2 = *(const bf16x8*)&vpB[(size_t)32 * NSEQ];
        bf16x8 vB3 = *(const bf16x8*)&vpB[(size_t)32 * NSEQ + 16];
        __builtin_amdgcn_s_setprio(1);
        o0 = __builtin_amdgcn_mfma_f32_32x32x16_bf16(vA0, b0.v, o0, 0, 0, 0);
        o1 = __builtin_amdgcn_mfma_f32_32x32x16_bf16(vA2, b0.v, o1, 0, 0, 0);
        o0 = __builtin_amdgcn_mfma_f32_32x32x16_bf16(vA1, b1.v, o0, 0, 0, 0);
        o1 = __builtin_amdgcn_mfma_f32_32x32x16_bf16(vA3, b1.v, o1, 0, 0, 0);
        o0 = __builtin_amdgcn_mfma_f32_32x32x16_bf16(vB0, b2.v, o0, 0, 0, 0);
        o1 = __builtin_amdgcn_mfma_f32_32x32x16_bf16(vB2, b2.v, o1, 0, 0, 0);
        o0 = __builtin_amdgcn_mfma_f32_32x32x16_bf16(vB1, b3.v, o0, 0, 0, 0);
        o1 = __builtin_amdgcn_mfma_f32_32x32x16_bf16(vB3, b3.v, o1, 0, 0, 0);
        __builtin_amdgcn_s_setprio(0);
    }
    lrun += __shfl_xor(lrun, 32);
    float inv = 1.0f / lrun;
    size_t obase = ((size_t)bidx * NSEQ + tq) * DIM + head * HD;
#pragma unroll
    for (int dt = 0; dt < 2; ++dt)
#pragma unroll
        for (int a = 0; a < 4; ++a) {
            union { bf16 h[4]; uint2 u; } pkd;
            const f32x16& ov = dt ? o1 : o0;
#pragma unroll
            for (int i = 0; i < 4; ++i) pkd.h[i] = __float2bfloat16(ov[4 * a + i] * inv);
            *(uint2*)&Ob[obase + dt * 32 + 8 * a + 4 * hi] = pkd.u;
        }
}

// ---------------------------------------------------------------- launch
extern "C" void kernel_launch(void* const* d_in, const int* in_sizes, int n_in,
                              void* d_out, int out_size, void* d_ws, size_t ws_size,
                              hipStream_t stream) {
    const float* x   = (const float*)d_in[0];
    const float* Wq  = (const float*)d_in[1];
    const float* Wkv = (const float*)d_in[2];
    const float* Wo  = (const float*)d_in[3];
    const float* bo  = (const float*)d_in[4];
    const float* Wo0 = (const float*)d_in[5];
    const float* bo0 = (const float*)d_in[6];
    float* out = (float*)d_out;

    char* ws = (char*)d_ws;
    size_t off = 0;
    auto alloc = [&](size_t bytes) { void* p = ws + off; off += (bytes + 255) & ~(size_t)255; return p; };
    float* cosT = (float*)alloc((size_t)NSEQ * 32 * 4);
    float* sinT = (float*)alloc((size_t)NSEQ * 32 * 4);
    bf16* Xb    = (bf16*)alloc((size_t)ROWS * DIM * 2);
    bf16* WqT   = (bf16*)alloc((size_t)DIM * DIM * 2);
    bf16* WkvT  = (bf16*)alloc((size_t)DIM * DIM * 2);
    bf16* WoT   = (bf16*)alloc((size_t)DIM * DIM * 2);
    bf16* Wo0T  = (bf16*)alloc((size_t)DIM * DIM * 2);
    bf16* Yq    = (bf16*)alloc((size_t)ROWS * DIM * 2);
    bf16* Ykv   = (bf16*)alloc((size_t)ROWS * DIM * 2);
    bf16* Qb    = (bf16*)alloc((size_t)NC * NSEQ * HD * 2);
    bf16* KVb   = (bf16*)alloc((size_t)NC * NSEQ * HD * 2);
    bf16* KVt   = (bf16*)alloc((size_t)NC * HD * NSEQ * 2);
    bf16* Ob    = (bf16*)alloc((size_t)ROWS * DIM * 2);

    hipLaunchKernelGGL(k_rope_tab, dim3(NSEQ * 32 / 256), dim3(256), 0, stream, cosT, sinT);
    hipLaunchKernelGGL(k_convert_x, dim3(ROWS * DIM / 4 / 256), dim3(256), 0, stream, x, Xb);
    hipLaunchKernelGGL(k_transpose, dim3(32, 32), dim3(32, 8), 0, stream, Wq, WqT);
    hipLaunchKernelGGL(k_transpose, dim3(32, 32), dim3(32, 8), 0, stream, Wkv, WkvT);
    hipLaunchKernelGGL(k_transpose, dim3(32, 32), dim3(32, 8), 0, stream, Wo, WoT);
    hipLaunchKernelGGL(k_transpose, dim3(32, 32), dim3(32, 8), 0, stream, Wo0, Wo0T);

    hipLaunchKernelGGL(k_gemm_qkv, dim3(1024), dim3(256), 0, stream, Xb, WqT, WkvT, Yq, Ykv);
    hipLaunchKernelGGL(k_rope_q, dim3(ROWS * DIM / 2 / 256), dim3(256), 0, stream, Yq, cosT, sinT, Qb);
    hipLaunchKernelGGL(k_rope_kv, dim3(16, 32), dim3(256), 0, stream, Ykv, cosT, sinT, KVb, KVt);

    hipLaunchKernelGGL(k_attn, dim3(1024), dim3(256), 0, stream, Qb, KVb, KVt, Ob);

    hipLaunchKernelGGL(k_gemm_out, dim3(512), dim3(256), 0, stream, Ob, Wo0T, WoT, bo0, bo, out);
}